// Round 1
// baseline (336.347 us; speedup 1.0000x reference)
//
#include <hip/hip_runtime.h>

// TinyAttention on MI355X: b=4, t=2048, d=1024, single head (head_dim=1024).
// All GEMMs in bf16 MFMA (16x16x32), m97-style 128x128 tile, global_load_lds(16B).
// Every GEMM is C[M,N] = A[M,K] * B[N,K]^T (BT form); weights pre-transposed.

typedef __bf16 bf16x8_t __attribute__((ext_vector_type(8)));
typedef float  f32x4_t  __attribute__((ext_vector_type(4)));
typedef unsigned short u16;

struct alignas(8) u16x4 { u16 x, y, z, w; };

__device__ inline float bf2f(u16 u) {
  union { unsigned u; float f; } c; c.u = ((unsigned)u) << 16; return c.f;
}
__device__ inline u16 f2bf(float f) {  // round-to-nearest-even
  union { float f; unsigned u; } c; c.f = f;
  unsigned r = c.u + 0x7fffu + ((c.u >> 16) & 1u);
  return (u16)(r >> 16);
}

// ---------------------------------------------------------------------------
// GEMM: C[M,N] = A[M,K] * B[N,K]^T.  Block = 128x128 tile, 256 threads
// (4 waves, each computes 64x64 via 4x4 grid of 16x16x32 bf16 MFMAs).
// CSKIP: skip blocks strictly above the causal diagonal (score GEMM).
// CKLIM: limit K to bm0+128 (PV GEMM; P is zero beyond the diagonal block).
// ---------------------------------------------------------------------------
template<bool OUT_F32, bool CSKIP, bool CKLIM, bool BIAS>
__global__ __launch_bounds__(256)
void gemm_bt(const u16* __restrict__ A, const u16* __restrict__ B,
             void* __restrict__ Cv, const float* __restrict__ bias,
             int K, int lda, int ldb, int ldc,
             long sA, long sB, long sC)
{
  const int bn0 = blockIdx.x * 128;
  const int bm0 = blockIdx.y * 128;
  if (CSKIP && bn0 > bm0) return;
  const long bz = blockIdx.z;
  const u16* Ab = A + bz * sA;
  const u16* Bb = B + bz * sB;
  const int Keff = CKLIM ? min(K, bm0 + 128) : K;

  __shared__ __align__(16) u16 lA[128 * 32];
  __shared__ __align__(16) u16 lB[128 * 32];

  const int tid  = threadIdx.x;
  const int lane = tid & 63;
  const int wv   = tid >> 6;
  const int wm   = (wv >> 1) << 6;   // wave's 64-row offset
  const int wn   = (wv & 1) << 6;    // wave's 64-col offset
  const int fr   = lane & 15;        // fragment row (A) / col (B,D)
  const int kq   = lane >> 4;        // k-quad 0..3

  f32x4_t acc[4][4];
#pragma unroll
  for (int i = 0; i < 4; ++i)
#pragma unroll
    for (int j = 0; j < 4; ++j)
      acc[i][j] = (f32x4_t){0.f, 0.f, 0.f, 0.f};

  const char* gA = (const char*)(Ab + (long)bm0 * lda);
  const char* gB = (const char*)(Bb + (long)bn0 * ldb);

  for (int k0 = 0; k0 < Keff; k0 += 32) {
    // stage 128x32 bf16 tiles of A and B: 8192 B each, 2 rounds x 256 lanes x 16 B
#pragma unroll
    for (int r = 0; r < 2; ++r) {
      const int bo  = (r * 256 + tid) * 16;  // byte offset in tile (lane-contiguous)
      const int row = bo >> 6;               // 64 B per 32-elem row
      const int cb  = bo & 63;
      __builtin_amdgcn_global_load_lds(
          (const __attribute__((address_space(1))) unsigned int*)
              (gA + (long)row * lda * 2 + (long)k0 * 2 + cb),
          (__attribute__((address_space(3))) unsigned int*)((char*)lA + bo),
          16, 0, 0);
      __builtin_amdgcn_global_load_lds(
          (const __attribute__((address_space(1))) unsigned int*)
              (gB + (long)row * ldb * 2 + (long)k0 * 2 + cb),
          (__attribute__((address_space(3))) unsigned int*)((char*)lB + bo),
          16, 0, 0);
    }
    __syncthreads();

    bf16x8_t af[4], bfr[4];
#pragma unroll
    for (int i = 0; i < 4; ++i)
      af[i]  = *(const bf16x8_t*)&lA[(wm + i * 16 + fr) * 32 + kq * 8];
#pragma unroll
    for (int j = 0; j < 4; ++j)
      bfr[j] = *(const bf16x8_t*)&lB[(wn + j * 16 + fr) * 32 + kq * 8];
#pragma unroll
    for (int i = 0; i < 4; ++i)
#pragma unroll
      for (int j = 0; j < 4; ++j)
        acc[i][j] = __builtin_amdgcn_mfma_f32_16x16x32_bf16(af[i], bfr[j], acc[i][j], 0, 0, 0);
    __syncthreads();
  }

  // epilogue: D layout col=lane&15, row=(lane>>4)*4+reg  [m89-verified]
  u16*   Cb16 = (u16*)Cv + bz * sC;
  float* Cf32 = (float*)Cv + bz * sC;
#pragma unroll
  for (int i = 0; i < 4; ++i) {
#pragma unroll
    for (int j = 0; j < 4; ++j) {
#pragma unroll
      for (int r = 0; r < 4; ++r) {
        const int row = bm0 + wm + i * 16 + kq * 4 + r;
        const int col = bn0 + wn + j * 16 + fr;
        float v = acc[i][j][r];
        if (BIAS) v += bias[col];
        if (OUT_F32) Cf32[(long)row * ldc + col] = v;
        else         Cb16[(long)row * ldc + col] = f2bf(v);
      }
    }
  }
}

// ---------------------------------------------------------------------------
// fp32 -> bf16 convert, float4 loads; grid sized exactly (n/4 threads)
// ---------------------------------------------------------------------------
__global__ __launch_bounds__(256)
void cvt_f32_bf16(const float* __restrict__ in, u16* __restrict__ out) {
  const int i = blockIdx.x * 256 + threadIdx.x;
  float4 v = ((const float4*)in)[i];
  u16x4 o = {f2bf(v.x), f2bf(v.y), f2bf(v.z), f2bf(v.w)};
  ((u16x4*)out)[i] = o;
}

// in [R,C] fp32 -> out [C,R] bf16
__global__ __launch_bounds__(256)
void transpose_f32_bf16(const float* __restrict__ in, u16* __restrict__ out,
                        int R, int C) {
  __shared__ float t[32][33];
  const int c0 = blockIdx.x * 32, r0 = blockIdx.y * 32;
  const int tx = threadIdx.x & 31, ty = threadIdx.x >> 5;
#pragma unroll
  for (int i = 0; i < 32; i += 8)
    t[ty + i][tx] = in[(long)(r0 + ty + i) * C + (c0 + tx)];
  __syncthreads();
#pragma unroll
  for (int i = 0; i < 32; i += 8)
    out[(long)(c0 + ty + i) * R + (r0 + tx)] = f2bf(t[tx][ty + i]);
}

// V slice of qkv [s=2048, d=1024] (ld 3072, col offset 2048) -> vT [d=1024, s=2048]
__global__ __launch_bounds__(256)
void transpose_v(const u16* __restrict__ qkv, u16* __restrict__ vT) {
  __shared__ u16 t[32][33];
  const int b = blockIdx.z;
  const u16* in = qkv + (long)b * 2048 * 3072 + 2048;
  u16* out      = vT  + (long)b * 1024 * 2048;
  const int c0 = blockIdx.x * 32, r0 = blockIdx.y * 32;
  const int tx = threadIdx.x & 31, ty = threadIdx.x >> 5;
#pragma unroll
  for (int i = 0; i < 32; i += 8)
    t[ty + i][tx] = in[(long)(r0 + ty + i) * 3072 + (c0 + tx)];
  __syncthreads();
#pragma unroll
  for (int i = 0; i < 32; i += 8)
    out[(long)(c0 + ty + i) * 2048 + (r0 + tx)] = t[tx][ty + i];
}

// ---------------------------------------------------------------------------
// Causal row softmax, in-place on bf16 S -> P.  One block per row.
// Applies 1/sqrt(d)=1/32 scale; zero-fills (t, 128-aligned row end) so the
// PV GEMM's K-limit (bm0+128) reads only valid data.
// ---------------------------------------------------------------------------
__global__ __launch_bounds__(256)
void softmax_causal(u16* __restrict__ SP) {
  const int t = blockIdx.x;
  const int b = blockIdx.y;
  u16* row = SP + ((long)b * 2048 + t) * 2048;
  const int len = t + 1;
  const int end = ((t >> 7) + 1) << 7;   // 128-aligned
  __shared__ float buf[2048];
  __shared__ float red[8];
  const int tid = threadIdx.x;
  const float scale = 0.03125f;          // 1/sqrt(1024)

  float lmax = -3.0e38f;
  for (int s0 = tid * 4; s0 < end; s0 += 1024) {
    u16x4 u = *(const u16x4*)(row + s0);
    float v[4] = {bf2f(u.x), bf2f(u.y), bf2f(u.z), bf2f(u.w)};
#pragma unroll
    for (int e = 0; e < 4; ++e) {
      const int s = s0 + e;
      if (s < len) { const float xx = v[e] * scale; buf[s] = xx; lmax = fmaxf(lmax, xx); }
    }
  }
#pragma unroll
  for (int o = 32; o; o >>= 1) lmax = fmaxf(lmax, __shfl_down(lmax, o));
  if ((tid & 63) == 0) red[tid >> 6] = lmax;
  __syncthreads();
  const float m = fmaxf(fmaxf(red[0], red[1]), fmaxf(red[2], red[3]));

  float lsum = 0.f;
  for (int s = tid; s < len; s += 256) {
    const float ev = __expf(buf[s] - m);
    buf[s] = ev;
    lsum += ev;
  }
#pragma unroll
  for (int o = 32; o; o >>= 1) lsum += __shfl_down(lsum, o);
  if ((tid & 63) == 0) red[4 + (tid >> 6)] = lsum;
  __syncthreads();
  const float inv = 1.0f / (red[4] + red[5] + red[6] + red[7]);

  for (int s0 = tid * 4; s0 < end; s0 += 1024) {
    u16x4 o;
    u16* pv = (u16*)&o;
#pragma unroll
    for (int e = 0; e < 4; ++e) {
      const int s = s0 + e;
      const float v = (s < len) ? buf[s] * inv : 0.f;
      pv[e] = f2bf(v);
    }
    *(u16x4*)(row + s0) = o;
  }
}

// ---------------------------------------------------------------------------
extern "C" void kernel_launch(void* const* d_in, const int* in_sizes, int n_in,
                              void* d_out, int out_size, void* d_ws, size_t ws_size,
                              hipStream_t stream) {
  (void)in_sizes; (void)n_in; (void)out_size; (void)ws_size;
  const float* x      = (const float*)d_in[0];
  const float* w_qkv  = (const float*)d_in[1];
  const float* w_proj = (const float*)d_in[2];
  const float* b_proj = (const float*)d_in[3];
  float* y = (float*)d_out;
  char*  ws = (char*)d_ws;

  // workspace layout (120 MB total)
  u16* xbf    = (u16*)(ws);                  // 16 MB  x in bf16; later reused for attn_out
  u16* qkv    = (u16*)(ws + (16l << 20));    // 48 MB  [8192, 3072] bf16
  u16* wqkvT  = (u16*)(ws + (64l << 20));    //  6 MB  [3072, 1024] bf16
  u16* wprojT = (u16*)(ws + (70l << 20));    //  2 MB  [1024, 1024] bf16
  u16* vT     = (u16*)(ws + (72l << 20));    // 16 MB  [4][1024, 2048] bf16
  u16* SP     = (u16*)(ws + (88l << 20));    // 32 MB  [4][2048, 2048] bf16 (S, then P in-place)
  u16* attn   = xbf;                         // lifetime-disjoint reuse (x dead after QKV GEMM)

  // 1) x -> bf16
  cvt_f32_bf16<<<8192, 256, 0, stream>>>(x, xbf);
  // 2) weights -> transposed bf16 ([N,K] for the BT GEMM)
  transpose_f32_bf16<<<dim3(96, 32), 256, 0, stream>>>(w_qkv, wqkvT, 1024, 3072);
  transpose_f32_bf16<<<dim3(32, 32), 256, 0, stream>>>(w_proj, wprojT, 1024, 1024);
  // 3) qkv = x @ w_qkv : M=8192 N=3072 K=1024
  gemm_bt<false, false, false, false><<<dim3(24, 64, 1), 256, 0, stream>>>(
      xbf, wqkvT, qkv, nullptr, 1024, 1024, 1024, 3072, 0, 0, 0);
  // 4) vT = transpose(v)
  transpose_v<<<dim3(32, 64, 4), 256, 0, stream>>>(qkv, vT);
  // 5) S = q @ k^T, batched, causal block skip: M=N=2048 K=1024
  gemm_bt<false, true, false, false><<<dim3(16, 16, 4), 256, 0, stream>>>(
      qkv, qkv + 1024, SP, nullptr, 1024, 3072, 3072, 2048,
      (long)2048 * 3072, (long)2048 * 3072, (long)2048 * 2048);
  // 6) P = softmax(S / 32) with causal mask, in place
  softmax_causal<<<dim3(2048, 4), 256, 0, stream>>>(SP);
  // 7) attn_out = P @ V : M=2048 N=1024 K<=bm0+128 (causal), batched
  gemm_bt<false, false, true, false><<<dim3(8, 16, 4), 256, 0, stream>>>(
      SP, vT, attn, nullptr, 2048, 2048, 2048, 1024,
      (long)2048 * 2048, (long)1024 * 2048, (long)2048 * 1024);
  // 8) y = attn_out @ w_proj + b_proj : M=8192 N=1024 K=1024, fp32 out
  gemm_bt<true, false, false, true><<<dim3(8, 64, 1), 256, 0, stream>>>(
      attn, wprojT, y, b_proj, 1024, 1024, 1024, 1024, 0, 0, 0);
}

// Round 2
// 308.240 us; speedup vs baseline: 1.0912x; 1.0912x over previous
//
#include <hip/hip_runtime.h>

// TinyAttention on MI355X: b=4, t=2048, d=1024, single head.
// All GEMMs bf16 MFMA 16x16x32, m97-style 128x128 tile, global_load_lds(16B).
// R2: compact triangular S grid, longest-first PV, V-transpose fused into QKV
// epilogue, register softmax, merged weight transposes.

typedef __bf16 bf16x8_t __attribute__((ext_vector_type(8)));
typedef float  f32x4_t  __attribute__((ext_vector_type(4)));
typedef unsigned short u16;

struct alignas(8) u16x4 { u16 x, y, z, w; };

__device__ inline float bf2f(u16 u) {
  union { unsigned u; float f; } c; c.u = ((unsigned)u) << 16; return c.f;
}
__device__ inline u16 f2bf(float f) {  // round-to-nearest-even
  union { float f; unsigned u; } c; c.f = f;
  unsigned r = c.u + 0x7fffu + ((c.u >> 16) & 1u);
  return (u16)(r >> 16);
}

// OUTMODE: 0 = bf16 row-major, 1 = f32 row-major + bias, 2 = QKV split
//          (bn0<2048 -> qk row-major bf16; bn0>=2048 -> vT col-major bf16)
// GRIDMODE: 0 = normal (bx=n-blk, by=m-blk, bz=batch)
//           1 = compact lower-triangular (bx=tri index, bz=batch)
//           2 = reversed-y m-blk + K limited to bm0+128 (PV)
template<int OUTMODE, int GRIDMODE>
__global__ __launch_bounds__(256)
void gemm_bt(const u16* __restrict__ A, const u16* __restrict__ B,
             void* __restrict__ Cv, u16* __restrict__ C2,
             const float* __restrict__ bias,
             int K, int lda, int ldb, int ldc,
             long sA, long sB, long sC)
{
  int bn0, bm0;
  if (GRIDMODE == 1) {
    const int x = blockIdx.x;                       // 0..135
    int r = (int)((sqrtf(8.f * x + 1.f) - 1.f) * 0.5f);
    while ((r + 1) * (r + 2) / 2 <= x) ++r;
    while (r * (r + 1) / 2 > x) --r;
    bm0 = r * 128;
    bn0 = (x - r * (r + 1) / 2) * 128;
  } else if (GRIDMODE == 2) {
    bn0 = blockIdx.x * 128;
    bm0 = ((int)gridDim.y - 1 - (int)blockIdx.y) * 128;  // longest K first
  } else {
    bn0 = blockIdx.x * 128;
    bm0 = blockIdx.y * 128;
  }
  const long bz = blockIdx.z;
  const u16* Ab = A + bz * sA;
  const u16* Bb = B + bz * sB;
  const int Keff = (GRIDMODE == 2) ? min(K, bm0 + 128) : K;

  __shared__ __align__(16) u16 lA[128 * 32];
  __shared__ __align__(16) u16 lB[128 * 32];

  const int tid  = threadIdx.x;
  const int lane = tid & 63;
  const int wv   = tid >> 6;
  const int wm   = (wv >> 1) << 6;   // wave's 64-row offset
  const int wn   = (wv & 1) << 6;    // wave's 64-col offset
  const int fr   = lane & 15;        // fragment row (A) / col (B,D)
  const int kq   = lane >> 4;        // k-quad 0..3

  f32x4_t acc[4][4];
#pragma unroll
  for (int i = 0; i < 4; ++i)
#pragma unroll
    for (int j = 0; j < 4; ++j)
      acc[i][j] = (f32x4_t){0.f, 0.f, 0.f, 0.f};

  // per-thread staging base pointers (hoisted out of K-loop)
  const char* gA = (const char*)(Ab + (long)bm0 * lda);
  const char* gB = (const char*)(Bb + (long)bn0 * ldb);
  const int bo0 = tid * 16, bo1 = (256 + tid) * 16;   // LDS byte offsets
  const int row0 = bo0 >> 6, cb0 = bo0 & 63;          // 64B per 32-elem row
  const int row1 = bo1 >> 6, cb1 = bo1 & 63;
  const char* pA0 = gA + (long)row0 * (lda * 2) + cb0;
  const char* pA1 = gA + (long)row1 * (lda * 2) + cb1;
  const char* pB0 = gB + (long)row0 * (ldb * 2) + cb0;
  const char* pB1 = gB + (long)row1 * (ldb * 2) + cb1;

  for (int k0 = 0; k0 < Keff; k0 += 32) {
    const long kb = (long)k0 * 2;
    __builtin_amdgcn_global_load_lds(
        (const __attribute__((address_space(1))) unsigned int*)(pA0 + kb),
        (__attribute__((address_space(3))) unsigned int*)((char*)lA + bo0), 16, 0, 0);
    __builtin_amdgcn_global_load_lds(
        (const __attribute__((address_space(1))) unsigned int*)(pB0 + kb),
        (__attribute__((address_space(3))) unsigned int*)((char*)lB + bo0), 16, 0, 0);
    __builtin_amdgcn_global_load_lds(
        (const __attribute__((address_space(1))) unsigned int*)(pA1 + kb),
        (__attribute__((address_space(3))) unsigned int*)((char*)lA + bo1), 16, 0, 0);
    __builtin_amdgcn_global_load_lds(
        (const __attribute__((address_space(1))) unsigned int*)(pB1 + kb),
        (__attribute__((address_space(3))) unsigned int*)((char*)lB + bo1), 16, 0, 0);
    __syncthreads();

    bf16x8_t af[4], bfr[4];
#pragma unroll
    for (int i = 0; i < 4; ++i)
      af[i]  = *(const bf16x8_t*)&lA[(wm + i * 16 + fr) * 32 + kq * 8];
#pragma unroll
    for (int j = 0; j < 4; ++j)
      bfr[j] = *(const bf16x8_t*)&lB[(wn + j * 16 + fr) * 32 + kq * 8];
#pragma unroll
    for (int i = 0; i < 4; ++i)
#pragma unroll
      for (int j = 0; j < 4; ++j)
        acc[i][j] = __builtin_amdgcn_mfma_f32_16x16x32_bf16(af[i], bfr[j], acc[i][j], 0, 0, 0);
    __syncthreads();
  }

  // epilogue: D layout col=lane&15, row=(lane>>4)*4+reg  [m89-verified]
  if (OUTMODE == 2 && bn0 >= 2048) {
    // V columns: write vT[batch][dcol][s] col-major, u16x4 over 4 consecutive rows
#pragma unroll
    for (int i = 0; i < 4; ++i) {
      const int rowb = bm0 + wm + i * 16 + kq * 4;   // 4 consecutive M rows
      const int b_  = rowb >> 11;                    // batch (t=2048)
      const int s_  = rowb & 2047;
#pragma unroll
      for (int j = 0; j < 4; ++j) {
        const int dcol = bn0 - 2048 + wn + j * 16 + fr;
        u16x4 o = {f2bf(acc[i][j][0]), f2bf(acc[i][j][1]),
                   f2bf(acc[i][j][2]), f2bf(acc[i][j][3])};
        *(u16x4*)&C2[(((long)b_ * 1024 + dcol) << 11) + s_] = o;
      }
    }
    return;
  }
  u16*   Cb16 = (u16*)Cv + bz * sC;
  float* Cf32 = (float*)Cv + bz * sC;
#pragma unroll
  for (int i = 0; i < 4; ++i) {
#pragma unroll
    for (int j = 0; j < 4; ++j) {
#pragma unroll
      for (int r = 0; r < 4; ++r) {
        const int row = bm0 + wm + i * 16 + kq * 4 + r;
        const int col = bn0 + wn + j * 16 + fr;
        float v = acc[i][j][r];
        if (OUTMODE == 1) {
          Cf32[(long)row * ldc + col] = v + bias[col];
        } else {
          Cb16[(long)row * ldc + col] = f2bf(v);
        }
      }
    }
  }
}

// ---------------------------------------------------------------------------
__global__ __launch_bounds__(256)
void cvt_f32_bf16(const float* __restrict__ in, u16* __restrict__ out) {
  const int i = blockIdx.x * 256 + threadIdx.x;
  float4 v = ((const float4*)in)[i];
  u16x4 o = {f2bf(v.x), f2bf(v.y), f2bf(v.z), f2bf(v.w)};
  ((u16x4*)out)[i] = o;
}

// both weight transposes in one dispatch: R=1024 rows each.
// blockIdx.x < 96 -> w_qkv [1024,3072] -> wqkvT [3072,1024]
// else            -> w_proj [1024,1024] -> wprojT [1024,1024]
__global__ __launch_bounds__(256)
void transpose_weights(const float* __restrict__ wqkv, u16* __restrict__ wqkvT,
                       const float* __restrict__ wproj, u16* __restrict__ wprojT) {
  const bool isq = blockIdx.x < 96;
  const float* in = isq ? wqkv : wproj;
  u16* out        = isq ? wqkvT : wprojT;
  const int C     = isq ? 3072 : 1024;
  const int c0 = (isq ? blockIdx.x : (blockIdx.x - 96)) * 32;
  const int r0 = blockIdx.y * 32;
  __shared__ float t[32][33];
  const int tx = threadIdx.x & 31, ty = threadIdx.x >> 5;
#pragma unroll
  for (int i = 0; i < 32; i += 8)
    t[ty + i][tx] = in[(long)(r0 + ty + i) * C + (c0 + tx)];
  __syncthreads();
#pragma unroll
  for (int i = 0; i < 32; i += 8)
    out[(long)(c0 + ty + i) * 1024 + (r0 + tx)] = f2bf(t[tx][ty + i]);
}

// ---------------------------------------------------------------------------
// Causal row softmax, in-place bf16 S -> P, fully register-resident.
// 256 threads x 8 elements = 2048 row. Applies 1/32 scale; zero-fills
// [len, 128-aligned end) so PV's K-limit reads only valid data.
// ---------------------------------------------------------------------------
__global__ __launch_bounds__(256)
void softmax_causal(u16* __restrict__ SP) {
  const int t = blockIdx.x;
  const int b = blockIdx.y;
  u16* row = SP + ((long)b * 2048 + t) * 2048;
  const int len = t + 1;
  const int end = ((t >> 7) + 1) << 7;   // 128-aligned
  const int tid = threadIdx.x;
  const int s0  = tid * 8;
  const float scale = 0.03125f;          // 1/sqrt(1024)
  __shared__ float red[8];

  float v[8];
  float lmax = -3.0e38f;
  if (s0 < end) {
    u16x4 u0 = *(const u16x4*)(row + s0);
    u16x4 u1 = *(const u16x4*)(row + s0 + 4);
    v[0] = bf2f(u0.x); v[1] = bf2f(u0.y); v[2] = bf2f(u0.z); v[3] = bf2f(u0.w);
    v[4] = bf2f(u1.x); v[5] = bf2f(u1.y); v[6] = bf2f(u1.z); v[7] = bf2f(u1.w);
#pragma unroll
    for (int e = 0; e < 8; ++e)
      if (s0 + e < len) { v[e] *= scale; lmax = fmaxf(lmax, v[e]); }
  }
#pragma unroll
  for (int o = 32; o; o >>= 1) lmax = fmaxf(lmax, __shfl_down(lmax, o));
  if ((tid & 63) == 0) red[tid >> 6] = lmax;
  __syncthreads();
  const float m = fmaxf(fmaxf(red[0], red[1]), fmaxf(red[2], red[3]));

  float lsum = 0.f;
  if (s0 < len) {
#pragma unroll
    for (int e = 0; e < 8; ++e)
      if (s0 + e < len) { v[e] = __expf(v[e] - m); lsum += v[e]; }
  }
#pragma unroll
  for (int o = 32; o; o >>= 1) lsum += __shfl_down(lsum, o);
  if ((tid & 63) == 0) red[4 + (tid >> 6)] = lsum;
  __syncthreads();
  const float inv = 1.0f / (red[4] + red[5] + red[6] + red[7]);

  if (s0 < end) {
    u16x4 o0, o1;
    u16* pv = (u16*)&o0;
#pragma unroll
    for (int e = 0; e < 8; ++e) {
      const float ve = (s0 + e < len) ? v[e] * inv : 0.f;
      ((u16*)&o0)[0]; // no-op; keep arrays simple
      if (e < 4) ((u16*)&o0)[e] = f2bf(ve);
      else       ((u16*)&o1)[e - 4] = f2bf(ve);
    }
    (void)pv;
    *(u16x4*)(row + s0)     = o0;
    *(u16x4*)(row + s0 + 4) = o1;
  }
}

// ---------------------------------------------------------------------------
extern "C" void kernel_launch(void* const* d_in, const int* in_sizes, int n_in,
                              void* d_out, int out_size, void* d_ws, size_t ws_size,
                              hipStream_t stream) {
  (void)in_sizes; (void)n_in; (void)out_size; (void)ws_size;
  const float* x      = (const float*)d_in[0];
  const float* w_qkv  = (const float*)d_in[1];
  const float* w_proj = (const float*)d_in[2];
  const float* b_proj = (const float*)d_in[3];
  float* y = (float*)d_out;
  char*  ws = (char*)d_ws;

  // workspace layout (104 MB)
  u16* xbf    = (u16*)(ws);                  // 16 MB  x bf16; reused for attn_out
  u16* qk     = (u16*)(ws + (16l << 20));    // 32 MB  [4][2048][2048] bf16 (q | k)
  u16* wqkvT  = (u16*)(ws + (48l << 20));    //  6 MB  [3072,1024]
  u16* wprojT = (u16*)(ws + (54l << 20));    //  2 MB  [1024,1024]
  u16* vT     = (u16*)(ws + (56l << 20));    // 16 MB  [4][1024][2048]
  u16* SP     = (u16*)(ws + (72l << 20));    // 32 MB  [4][2048][2048] S->P in place
  u16* attn   = xbf;                         // lifetime-disjoint reuse

  // 1) x -> bf16
  cvt_f32_bf16<<<8192, 256, 0, stream>>>(x, xbf);
  // 2) weights -> transposed bf16 (one dispatch)
  transpose_weights<<<dim3(128, 32), 256, 0, stream>>>(w_qkv, wqkvT, w_proj, wprojT);
  // 3) qkv = x @ w_qkv : M=8192 N=3072 K=1024; q,k -> qk (ldc 2048), v -> vT fused
  gemm_bt<2, 0><<<dim3(24, 64, 1), 256, 0, stream>>>(
      xbf, wqkvT, qk, vT, nullptr, 1024, 1024, 1024, 2048, 0, 0, 0);
  // 4) S = q @ k^T, compact lower-triangular grid: 136 blocks x 4 batches
  gemm_bt<0, 1><<<dim3(136, 1, 4), 256, 0, stream>>>(
      qk, qk + 1024, SP, nullptr, nullptr, 1024, 2048, 2048, 2048,
      (long)2048 * 2048, (long)2048 * 2048, (long)2048 * 2048);
  // 5) P = softmax(S / 32), causal, in place, register-resident
  softmax_causal<<<dim3(2048, 4), 256, 0, stream>>>(SP);
  // 6) attn = P @ V : K_eff = bm0+128, longest blocks dispatched first
  gemm_bt<0, 2><<<dim3(8, 16, 4), 256, 0, stream>>>(
      SP, vT, attn, nullptr, nullptr, 2048, 2048, 2048, 1024,
      (long)2048 * 2048, (long)1024 * 2048, (long)2048 * 1024);
  // 7) y = attn @ w_proj + b_proj : fp32 out
  gemm_bt<1, 0><<<dim3(8, 64, 1), 256, 0, stream>>>(
      attn, wprojT, y, nullptr, b_proj, 1024, 1024, 1024, 1024, 0, 0, 0);
}